// Round 5
// baseline (266.201 us; speedup 1.0000x reference)
//
#include <hip/hip_runtime.h>
#include <stdint.h>

// N=16384 points, K=10 (fixed by setup_inputs).
#define NPTS   16384
#define TOPK   10
#define NGRID  128                 // 128x128 Morton cells -> 14-bit cid
#define NCELL  (NGRID * NGRID)
#define XMIN   (-5.0f)
#define INVW   (12.8f)
#define MASK14 0xFFFFC000u
#define NCHUNK 8
#define CHK    (NPTS / NCHUNK)     // 2048 candidates per chunk

// ws layout (bytes) — partial overlays the sort scratch (dead before pass2):
//   0       accum[4] floats; 16: ticket uint          [0,256)    (zeroed)
//   256     r2m[NPTS] uint                            [256,65792)
//   65792   sorted[NPTS] float4 (x,y,z,opacity)       [65792,327936)
//   327936  partial[NCHUNK][NPTS][TOPK] uint          [327936,5570816)
//     overlaid sort scratch (all dead once pass2 runs):
//     327936 hist[NCELL] uint    (zeroed)
//     393472 cnt[NCELL]  uint    (zeroed)
//     459008 base[NCELL+1] uint
//     524672 cid[NPTS] int
// total 5,570,816 B  (< round-0's proven 5.77 MB usage)

__device__ __forceinline__ unsigned umin_(unsigned a, unsigned b) { return a < b ? a : b; }
__device__ __forceinline__ unsigned umax_(unsigned a, unsigned b) { return a > b ? a : b; }

// Branchless ascending insert; inserting key >= a[TOPK-1] is a no-op, so no
// per-lane gate is needed when called under a wave-level __any branch.
__device__ __forceinline__ void chain_insert(unsigned (&a)[TOPK], unsigned key) {
#pragma unroll
    for (int k = TOPK - 1; k > 0; --k) a[k] = umin_(umax_(a[k - 1], key), a[k]);
    a[0] = umin_(a[0], key);
}

__device__ __forceinline__ unsigned spread7(unsigned x) {
    x &= 0xFFu;
    x = (x | (x << 4)) & 0x0F0Fu;
    x = (x | (x << 2)) & 0x3333u;
    x = (x | (x << 1)) & 0x5555u;
    return x;
}

// ---- fused trivial losses + Morton-cell histogram -------------------------
__global__ __launch_bounds__(256) void setup_kernel(
    const float* __restrict__ pos, const float* __restrict__ opac,
    const float* __restrict__ scales, float* __restrict__ accum,
    unsigned* __restrict__ hist, int* __restrict__ cid)
{
    int i = blockIdx.x * 256 + threadIdx.x;
    float o = opac[i];
    float d = o - 0.5f;
    float s_sp = fabsf(o);
    float s_op = d * d;
    float s_sc = fabsf(scales[3 * i] - 1.0f) + fabsf(scales[3 * i + 1] - 1.0f)
               + fabsf(scales[3 * i + 2] - 1.0f);
    float x = pos[3 * i], y = pos[3 * i + 1];
    int bx = min(max((int)((x - XMIN) * INVW), 0), NGRID - 1);
    int by = min(max((int)((y - XMIN) * INVW), 0), NGRID - 1);
    int c = (int)(spread7((unsigned)bx) | (spread7((unsigned)by) << 1));
    cid[i] = c;
    atomicAdd(&hist[c], 1u);
#pragma unroll
    for (int off = 32; off > 0; off >>= 1) {
        s_sp += __shfl_down(s_sp, off, 64);
        s_sc += __shfl_down(s_sc, off, 64);
        s_op += __shfl_down(s_op, off, 64);
    }
    if ((threadIdx.x & 63) == 0) {
        atomicAdd(&accum[0], s_sp);
        atomicAdd(&accum[1], s_sc);
        atomicAdd(&accum[2], s_op);
    }
}

// ---- exclusive prefix over 16384 cells, single block ----------------------
__global__ __launch_bounds__(1024) void prefix_cells(
    const unsigned* __restrict__ hist, unsigned* __restrict__ base)
{
    __shared__ unsigned bs[1024];
    int t = threadIdx.x;
    unsigned loc[16];
    unsigned run = 0;
#pragma unroll
    for (int k = 0; k < 16; ++k) { loc[k] = hist[t * 16 + k]; run += loc[k]; }
    bs[t] = run;
    __syncthreads();
    for (int off = 1; off < 1024; off <<= 1) {
        unsigned v = (t >= off) ? bs[t - off] : 0u;
        __syncthreads();
        bs[t] += v;
        __syncthreads();
    }
    unsigned acc = bs[t] - run;
#pragma unroll
    for (int k = 0; k < 16; ++k) { base[t * 16 + k] = acc; acc += loc[k]; }
    if (t == 1023) base[NCELL] = acc;
}

__global__ __launch_bounds__(256) void scatter_sorted(
    const float* __restrict__ pos, const float* __restrict__ opac,
    const int* __restrict__ cid, const unsigned* __restrict__ base,
    unsigned* __restrict__ cnt, float4* __restrict__ sorted)
{
    int i = blockIdx.x * 256 + threadIdx.x;
    int c = cid[i];
    unsigned p = base[c] + atomicAdd(&cnt[c], 1u);
    sorted[p] = make_float4(pos[3 * i], pos[3 * i + 1], pos[3 * i + 2], opac[i]);
}

// ---- pass 1: per-point upper bound from a wave-shared 256-window ----------
// All 64 lanes of the wave scan the SAME (wave-uniform) candidate window
// [wbase-96, wbase+160) in Morton order -> scalar candidate loads. Any 10
// distinct non-self candidates give a valid upper bound on the true d10.
__global__ __launch_bounds__(64) void knn_pass1(
    const float4* __restrict__ sorted, unsigned* __restrict__ r2m)
{
    const int wbase = blockIdx.x * 64;
    const int s = wbase + threadIdx.x;
    const float4 me = sorted[s];

    unsigned a[TOPK];
#pragma unroll
    for (int k = 0; k < TOPK; ++k) a[k] = 0xFFFFFFFFu;

#pragma unroll 4
    for (int t = 0; t < 256; ++t) {
        int pc = (wbase - 96 + t) & (NPTS - 1);   // wave-uniform, distinct
        float4 c = sorted[pc];
        float dx = c.x - me.x, dy = c.y - me.y, dz = c.z - me.z;
        float d2 = fmaf(dx, dx, fmaf(dy, dy, dz * dz));
        unsigned key = (__float_as_uint(d2) & MASK14) | (unsigned)pc;
        if (pc == s) key = 0xFFFFFFFFu;
        chain_insert(a, key);
    }
    r2m[s] = a[TOPK - 1];
}

// ---- pass 2: gated brute-force scan of one 2048-candidate chunk -----------
// Wave-uniform candidate stream; insert chain entered only via wave-level
// __any (true scalar branch). Gate seeded from pass1 bound, tightens as
// inserts land. Exact: a true NN is only ever rejected if 10 closer keys
// are already present in the same chunk list.
__global__ __launch_bounds__(256) void knn_pass2(
    const float4* __restrict__ sorted, const unsigned* __restrict__ r2m,
    unsigned* __restrict__ partial)
{
    const int s = blockIdx.x * 256 + threadIdx.x;     // consecutive per wave
    const int cbase = blockIdx.y * CHK;
    const float4 me = sorted[s];

    const unsigned sent = (r2m[s] & MASK14) + 0x8000u;  // > true d10 key
    unsigned a[TOPK];
#pragma unroll
    for (int k = 0; k < TOPK; ++k) a[k] = sent;
    float gatef = __uint_as_float((sent & MASK14) + 0x4000u);

    for (int t = 0; t < CHK; t += 4) {
        const int pc = cbase + t;
        float4 c0 = sorted[pc];
        float4 c1 = sorted[pc + 1];
        float4 c2 = sorted[pc + 2];
        float4 c3 = sorted[pc + 3];
        float dx0 = c0.x - me.x, dy0 = c0.y - me.y, dz0 = c0.z - me.z;
        float dx1 = c1.x - me.x, dy1 = c1.y - me.y, dz1 = c1.z - me.z;
        float dx2 = c2.x - me.x, dy2 = c2.y - me.y, dz2 = c2.z - me.z;
        float dx3 = c3.x - me.x, dy3 = c3.y - me.y, dz3 = c3.z - me.z;
        float d20 = fmaf(dx0, dx0, fmaf(dy0, dy0, dz0 * dz0));
        float d21 = fmaf(dx1, dx1, fmaf(dy1, dy1, dz1 * dz1));
        float d22 = fmaf(dx2, dx2, fmaf(dy2, dy2, dz2 * dz2));
        float d23 = fmaf(dx3, dx3, fmaf(dy3, dy3, dz3 * dz3));
        float dmin = fminf(fminf(d20, d21), fminf(d22, d23));
        if (__any(dmin < gatef)) {
            unsigned k0 = (__float_as_uint(d20) & MASK14) | (unsigned)(pc);
            unsigned k1 = (__float_as_uint(d21) & MASK14) | (unsigned)(pc + 1);
            unsigned k2 = (__float_as_uint(d22) & MASK14) | (unsigned)(pc + 2);
            unsigned k3 = (__float_as_uint(d23) & MASK14) | (unsigned)(pc + 3);
            if (pc     == s) k0 = 0xFFFFFFFFu;
            if (pc + 1 == s) k1 = 0xFFFFFFFFu;
            if (pc + 2 == s) k2 = 0xFFFFFFFFu;
            if (pc + 3 == s) k3 = 0xFFFFFFFFu;
            if (__any(k0 < a[TOPK - 1])) chain_insert(a, k0);
            if (__any(k1 < a[TOPK - 1])) chain_insert(a, k1);
            if (__any(k2 < a[TOPK - 1])) chain_insert(a, k2);
            if (__any(k3 < a[TOPK - 1])) chain_insert(a, k3);
            gatef = __uint_as_float((a[TOPK - 1] & MASK14) + 0x4000u);
        }
    }

    unsigned* dst = partial + ((size_t)blockIdx.y * NPTS + s) * TOPK;
#pragma unroll
    for (int k = 0; k < TOPK; ++k) dst[k] = a[k];
}

// ---- merge 8 chunk lists per point + smoothness + fused combine -----------
__global__ __launch_bounds__(256) void knn_merge(
    const float4* __restrict__ sorted, const unsigned* __restrict__ partial,
    float* __restrict__ accum, unsigned* __restrict__ ticket,
    float* __restrict__ out)
{
    const int s = blockIdx.x * 256 + threadIdx.x;
    unsigned a[TOPK];
#pragma unroll
    for (int k = 0; k < TOPK; ++k) a[k] = 0xFFFFFFFFu;

#pragma unroll
    for (int c = 0; c < NCHUNK; ++c) {
        const unsigned* src = partial + ((size_t)c * NPTS + s) * TOPK;
#pragma unroll
        for (int k = 0; k < TOPK; ++k) chain_insert(a, src[k]);
    }

    const float oi = sorted[s].w;
    float v = 0.0f;
#pragma unroll
    for (int k = 0; k < TOPK; ++k) {
        int j = (int)(a[k] & 0x3FFFu);
        v += fabsf(oi - sorted[j].w);
    }
#pragma unroll
    for (int off = 32; off > 0; off >>= 1) v += __shfl_down(v, off, 64);
    if ((threadIdx.x & 63) == 0) atomicAdd(&accum[3], v);

    __syncthreads();
    if (threadIdx.x == 0) {
        __threadfence();
        unsigned tk = atomicAdd(ticket, 1u);
        if (tk == gridDim.x - 1) {
            float sp = atomicAdd(&accum[0], 0.0f);
            float sc = atomicAdd(&accum[1], 0.0f);
            float op = atomicAdd(&accum[2], 0.0f);
            float sm = atomicAdd(&accum[3], 0.0f);
            const float n = (float)NPTS;
            out[0] = 0.01f * (sp / n) + 0.1f * (sm / (n * 10.0f))
                   + sc / (3.0f * n) + op / n;
        }
    }
}

extern "C" void kernel_launch(void* const* d_in, const int* in_sizes, int n_in,
                              void* d_out, int out_size, void* d_ws, size_t ws_size,
                              hipStream_t stream)
{
    const float* pos    = (const float*)d_in[0];
    const float* opac   = (const float*)d_in[1];
    const float* scales = (const float*)d_in[2];
    float* out = (float*)d_out;

    char* ws = (char*)d_ws;
    float*    accum   = (float*)ws;
    unsigned* ticket  = (unsigned*)(ws + 16);
    unsigned* r2m     = (unsigned*)(ws + 256);
    float4*   sorted  = (float4*)(ws + 65792);
    unsigned* partial = (unsigned*)(ws + 327936);
    // sort scratch overlaid on the partial region (dead before pass2 writes)
    unsigned* hist    = (unsigned*)(ws + 327936);
    unsigned* cnt     = (unsigned*)(ws + 393472);
    unsigned* base    = (unsigned*)(ws + 459008);
    int*      cid     = (int*)(ws + 524672);

    hipMemsetAsync(ws, 0, 256, stream);               // accum + ticket
    hipMemsetAsync(ws + 327936, 0, 131072, stream);   // hist + cnt

    setup_kernel  <<<NPTS / 256, 256, 0, stream>>>(pos, opac, scales, accum, hist, cid);
    prefix_cells  <<<1, 1024, 0, stream>>>(hist, base);
    scatter_sorted<<<NPTS / 256, 256, 0, stream>>>(pos, opac, cid, base, cnt, sorted);
    knn_pass1     <<<NPTS / 64, 64, 0, stream>>>(sorted, r2m);
    dim3 g2(NPTS / 256, NCHUNK);
    knn_pass2     <<<g2, 256, 0, stream>>>(sorted, r2m, partial);
    knn_merge     <<<NPTS / 256, 256, 0, stream>>>(sorted, partial, accum, ticket, out);
}